// Round 8
// baseline (307.242 us; speedup 1.0000x reference)
//
#include <hip/hip_runtime.h>
#include <hip/hip_fp16.h>

#define WPB 8     // waves per sage block (512 threads)
#define PADK 136  // f16 elems per LDS row: 128 + 8 pad (16B-aligned rows)
#define BSH 8     // bucket shift: 256 nodes per bucket
#define BNODES 256
#define SC_BLOCKS 256   // MUST equal HIST_BLOCKS (chunk mapping shared)
#define HIST_BLOCKS 256
#define HSTRIDE 512     // padded bucket stride in hist_all / blk_base_all
#define PSTAGE 12288    // csr: LDS-staged pairs capacity (48KB)
#define SCAP 7168       // scatter: max edges per block chunk (ceil(E/4/65536)*1024*4 edges -> 7*1024)

typedef _Float16 half8 __attribute__((ext_vector_type(8)));
typedef _Float16 half4v __attribute__((ext_vector_type(4)));
typedef float floatx4 __attribute__((ext_vector_type(4)));

// ---------------- pre: hist (blocks 0..255, persisted per-block) + x->f16 cvt (rest) ----------------
// Edge chunk mapping (int4 when E%4==0) MUST match gnn_bkt_scatter exactly.
__global__ __launch_bounds__(256) void gnn_pre(const int* __restrict__ dst,
                                               int* __restrict__ bkt_cnt, int nbkt, int E,
                                               const int* __restrict__ batch,
                                               float* __restrict__ gcnt, int N,
                                               const float4* __restrict__ xin,
                                               ushort4* __restrict__ x16o, int n4,
                                               __half* __restrict__ x16,
                                               __half* __restrict__ hA,
                                               __half* __restrict__ hB,
                                               int* __restrict__ hist_all) {
    int tid = threadIdx.x;
    if (blockIdx.x < HIST_BLOCKS) {
        __shared__ int h[512];
        __shared__ int gb[64];
        for (int i = tid; i < nbkt; i += 256) h[i] = 0;
        if (tid < 64) gb[tid] = 0;
        __syncthreads();
        const int stride = HIST_BLOCKS * 256;
        if ((E & 3) == 0) {
            const int4* dst4 = (const int4*)dst;
            int E4 = E >> 2;
            for (int e = blockIdx.x * 256 + tid; e < E4; e += stride) {
                int4 d = dst4[e];
                atomicAdd(&h[d.x >> BSH], 1);
                atomicAdd(&h[d.y >> BSH], 1);
                atomicAdd(&h[d.z >> BSH], 1);
                atomicAdd(&h[d.w >> BSH], 1);
            }
        } else {
            for (int e = blockIdx.x * 256 + tid; e < E; e += stride)
                atomicAdd(&h[dst[e] >> BSH], 1);
        }
        for (int i = blockIdx.x * 256 + tid; i < N; i += stride)
            atomicAdd(&gb[batch[i]], 1);
        __syncthreads();
        for (int i = tid; i < nbkt; i += 256) {
            int v = h[i];
            hist_all[blockIdx.x * HSTRIDE + i] = v;  // persist per-block chunk histogram
            if (v) atomicAdd(&bkt_cnt[i], v);
        }
        if (tid < 64) {
            int v = gb[tid];
            if (v) atomicAdd(&gcnt[tid], (float)v);
        }
        if (blockIdx.x == 0 && tid < 64) {  // zero sentinel row N of x16, hA, hB
            x16[(size_t)N * 64 + tid] = __ushort_as_half((unsigned short)0);
            hA[(size_t)N * 64 + tid] = __ushort_as_half((unsigned short)0);
            hB[(size_t)N * 64 + tid] = __ushort_as_half((unsigned short)0);
        }
    } else {
        int i = (blockIdx.x - HIST_BLOCKS) * 256 + tid;
        if (i < n4) {
            float4 f = xin[i];
            ushort4 o;
            o.x = __half_as_ushort(__float2half(f.x));
            o.y = __half_as_ushort(__float2half(f.y));
            o.z = __half_as_ushort(__float2half(f.z));
            o.w = __half_as_ushort(__float2half(f.w));
            x16o[i] = o;
        }
    }
}

// ---------------- scan2: per-bucket exclusive scan over blocks -> exact scatter bases.
// Also computes bkt_base[b] per block (reduction of bkt_cnt[<b]) — no separate scan kernel.
__global__ __launch_bounds__(256) void gnn_scan2(const int* __restrict__ hist_all,
                                                 const int* __restrict__ bkt_cnt,
                                                 int* __restrict__ bkt_base,
                                                 int* __restrict__ row_ptr,
                                                 int* __restrict__ blk_base_all,
                                                 int nbkt, int N) {
    int b = blockIdx.x;
    int t = threadIdx.x, lane = t & 63, wv = t >> 6;
    __shared__ int wsum[4];
    __shared__ int red[4];
    // partial sum of bkt_cnt[0..b-1]
    int part = 0;
    for (int i = t; i < b; i += 256) part += bkt_cnt[i];
#pragma unroll
    for (int off = 1; off < 64; off <<= 1) part += __shfl_xor(part, off);
    if (lane == 0) red[wv] = part;
    // per-chunk scan of this bucket's histogram column
    int v = hist_all[t * HSTRIDE + b];
    int x = v;
#pragma unroll
    for (int off = 1; off < 64; off <<= 1) {
        int y = __shfl_up(x, off);
        if (lane >= off) x += y;
    }
    if (lane == 63) wsum[wv] = x;
    __syncthreads();
    int base = red[0] + red[1] + red[2] + red[3];
    int wexcl = 0;
    for (int w = 0; w < wv; w++) wexcl += wsum[w];
    blk_base_all[t * HSTRIDE + b] = base + wexcl + (x - v);
    if (t == 0) {
        bkt_base[b] = base;
        if (b == nbkt - 1) {
            int tot = base + bkt_cnt[b];
            bkt_base[nbkt] = tot;
            row_ptr[N] = tot;
        }
    }
}

// ---------------- scatter (R7: block-local counting sort in LDS -> coalesced burst writes).
// Kills the ~32x write amplification of random 4B global stores: sort this block's edges
// by bucket in LDS, then flush each bucket's run contiguously (one wave per bucket).
__global__ __launch_bounds__(256) void gnn_bkt_scatter(const int* __restrict__ src,
                                                       const int* __restrict__ dst,
                                                       const int* __restrict__ hist_all,
                                                       const int* __restrict__ blk_base_all,
                                                       unsigned int* __restrict__ pairs,
                                                       int E, int nbkt) {
    __shared__ unsigned int lp[SCAP];
    __shared__ int lexcl[512];
    __shared__ int cur[512];
    int tid = threadIdx.x, lane = tid & 63, wv = tid >> 6;
    int blk = blockIdx.x;
    for (int i = tid; i < nbkt; i += 256) cur[i] = hist_all[blk * HSTRIDE + i];
    __syncthreads();
    if (wv == 0) {  // local exclusive prefix over this block's histogram (1 wave, chunked)
        int carry = 0;
        for (int c0 = 0; c0 < nbkt; c0 += 64) {
            int idx = c0 + lane;
            int v = (idx < nbkt) ? cur[idx] : 0;
            int x = v;
#pragma unroll
            for (int off = 1; off < 64; off <<= 1) {
                int y = __shfl_up(x, off);
                if (lane >= off) x += y;
            }
            if (idx < nbkt) lexcl[idx] = carry + (x - v);
            carry += __shfl(x, 63);
        }
    }
    __syncthreads();
    for (int i = tid; i < nbkt; i += 256) cur[i] = lexcl[i];
    __syncthreads();
    const int stride = SC_BLOCKS * 256;  // SAME chunk mapping as gnn_pre's histogram
    if ((E & 3) == 0) {
        const int4* dst4 = (const int4*)dst;
        const int4* src4 = (const int4*)src;
        int E4 = E >> 2;
        for (int e = blk * 256 + tid; e < E4; e += stride) {
            int4 d = dst4[e];
            int4 s = src4[e];
            int p0 = atomicAdd(&cur[d.x >> BSH], 1);
            lp[p0] = (unsigned int)s.x | ((unsigned int)(d.x & (BNODES - 1)) << 24);
            int p1 = atomicAdd(&cur[d.y >> BSH], 1);
            lp[p1] = (unsigned int)s.y | ((unsigned int)(d.y & (BNODES - 1)) << 24);
            int p2 = atomicAdd(&cur[d.z >> BSH], 1);
            lp[p2] = (unsigned int)s.z | ((unsigned int)(d.z & (BNODES - 1)) << 24);
            int p3 = atomicAdd(&cur[d.w >> BSH], 1);
            lp[p3] = (unsigned int)s.w | ((unsigned int)(d.w & (BNODES - 1)) << 24);
        }
    } else {
        for (int e = blk * 256 + tid; e < E; e += stride) {
            int d = dst[e];
            int b = d >> BSH;
            int p = atomicAdd(&cur[b], 1);
            lp[p] = (unsigned int)src[e] | ((unsigned int)(d & (BNODES - 1)) << 24);
        }
    }
    __syncthreads();
    // flush: one wave per bucket -> contiguous coalesced runs (avg ~16 entries)
    for (int b = wv; b < nbkt; b += 4) {
        int base = lexcl[b];
        int cnt = cur[b] - base;  // cur ended at lexcl[b] + h[b]
        int g0 = blk_base_all[blk * HSTRIDE + b];
        for (int i = lane; i < cnt; i += 64) pairs[g0 + i] = lp[base + i];
    }
}

// ---------------- per-bucket CSR finalize (pairs staged in LDS once, both passes local) ----
__global__ __launch_bounds__(256) void gnn_bkt_csr(const unsigned int* __restrict__ pairs,
                                                   const int* __restrict__ bkt_base,
                                                   int* __restrict__ row_ptr,
                                                   float* __restrict__ inv_deg,
                                                   int* __restrict__ csr_src, int N) {
    __shared__ int hist[BNODES];
    __shared__ int excl[BNODES];
    __shared__ int cur[BNODES];
    __shared__ unsigned int pstage[PSTAGE];
    int b = blockIdx.x;
    int base = bkt_base[b];
    int cnt = bkt_base[b + 1] - base;
    int nd0 = b << BSH;
    int tid = threadIdx.x;
    hist[tid] = 0;
    __syncthreads();
    int scnt = min(cnt, PSTAGE);
    for (int i = tid; i < scnt; i += 256) {
        unsigned int u = pairs[base + i];
        pstage[i] = u;
        atomicAdd(&hist[u >> 24], 1);
    }
    for (int i = scnt + tid; i < cnt; i += 256)  // overflow fallback (P~0)
        atomicAdd(&hist[pairs[base + i] >> 24], 1);
    __syncthreads();
    if (tid < 64) {
        int carry = 0;
#pragma unroll
        for (int c = 0; c < BNODES; c += 64) {
            int v = hist[c + tid];
            int x = v;
#pragma unroll
            for (int off = 1; off < 64; off <<= 1) {
                int y = __shfl_up(x, off);
                if (tid >= off) x += y;
            }
            excl[c + tid] = carry + (x - v);
            carry += __shfl(x, 63);
        }
    }
    __syncthreads();
    {
        int node = nd0 + tid;
        if (node < N) {
            row_ptr[node] = base + excl[tid];
            int d = hist[tid];
            inv_deg[node] = 1.0f / (float)(d > 1 ? d : 1);
        }
        cur[tid] = excl[tid];
    }
    __syncthreads();
    for (int i = tid; i < scnt; i += 256) {
        unsigned int u = pstage[i];
        int pos = atomicAdd(&cur[u >> 24], 1);
        csr_src[base + pos] = (int)(u & 0xFFFFFFu);
    }
    for (int i = scnt + tid; i < cnt; i += 256) {
        unsigned int u = pairs[base + i];
        int pos = atomicAdd(&cur[u >> 24], 1);
        csr_src[base + pos] = (int)(u & 0xFFFFFFu);
    }
}

// load batch of one 16-slot chunk (4 dwordx2 loads, 4 rows each) into vArr
#define LOAD4(eReg, c0, vArr)                                  \
    _Pragma("unroll") for (int c_ = 0; c_ < 4; c_++) {         \
        int sj_ = __shfl(eReg, (c0) + c_ * 4 + quad);          \
        vArr[c_] = hin4v[(size_t)sj_ * 16 + m16];              \
    }
// consume batch
#define ACC4(vArr, accum)                                      \
    _Pragma("unroll") for (int c_ = 0; c_ < 4; c_++) {         \
        accum.x += (float)vArr[c_][0];                         \
        accum.y += (float)vArr[c_][1];                         \
        accum.z += (float)vArr[c_][2];                         \
        accum.w += (float)vArr[c_][3];                         \
    }

// ---------------- SAGE layer (R3-verbatim: proven 51us/layer — near random-line service floor) ----
__global__ __launch_bounds__(512, 4) void gnn_sage(const __half* __restrict__ hin,
                                                   __half* __restrict__ hout,
                                                   const int* __restrict__ row_ptr,
                                                   const int* __restrict__ csr_src,
                                                   const float* __restrict__ inv_deg,
                                                   const float* __restrict__ Wl,
                                                   const float* __restrict__ bl,
                                                   const float* __restrict__ Wr, int n) {
    __shared__ _Float16 w_lds[64 * PADK];
    __shared__ _Float16 in_lds[WPB][16 * PADK];
    int tid = threadIdx.x, lane = tid & 63, wv = tid >> 6;
    for (int i = tid; i < 64 * 64; i += 512) {
        int k = i >> 6, nn = i & 63;
        w_lds[nn * PADK + k] = (_Float16)Wl[i];
        w_lds[nn * PADK + 64 + k] = (_Float16)Wr[i];
    }
    __syncthreads();
    int ngroups = (n + 15) >> 4;
    int g = blockIdx.x * WPB + wv;
    if (g >= ngroups) return;
    int m16 = lane & 15, quad = lane >> 4;
    int hf = lane >> 5, col = lane & 31;
    float bias[4];
#pragma unroll
    for (int nt = 0; nt < 4; nt++) bias[nt] = bl[nt * 16 + m16];
    _Float16* my_in = in_lds[wv];
    const unsigned* hin32 = (const unsigned*)hin;
    const half4v* hin4v = (const half4v*)hin;
    int nd0 = g << 4;
    int nclamp = n - 1 - nd0;  // >= 0
    int idx = nd0 + lane;
    int rr = (lane <= 16) ? row_ptr[min(idx, n)] : 0;
    float ig = (lane < 16) ? inv_deg[min(idx, n - 1)] : 0.0f;

    // root rows -> LDS cols 64..127 (dword copies, 2 rows per load)
#pragma unroll
    for (int jp = 0; jp < 8; jp++) {
        int j2 = jp << 1;
        int nd = nd0 + min(j2 + hf, nclamp);
        unsigned u = hin32[(size_t)nd * 32 + col];
        ((unsigned*)(my_in + (j2 + hf) * PADK + 64))[col] = u;
    }

    // first-64 neighbor indices for all 16 nodes, hoisted (sentinel n beyond degree)
    int ef[16];
#pragma unroll
    for (int j = 0; j < 16; j++) {
        int jj = min(j, nclamp);
        int s0 = __shfl(rr, jj), s1 = __shfl(rr, jj + 1);
        int cb = min(64, s1 - s0);
        ef[j] = (lane < cb) ? csr_src[s0 + lane] : n;
    }

#pragma unroll
    for (int jp = 0; jp < 8; jp++) {
        int j2 = jp << 1;
        int jjA = min(j2, nclamp), jjB = min(j2 + 1, nclamp);
        int s0A = __shfl(rr, jjA), s1A = __shfl(rr, jjA + 1);
        int s0B = __shfl(rr, jjB), s1B = __shfl(rr, jjB + 1);
        float idgA = __shfl(ig, jjA), idgB = __shfl(ig, jjB);
        int cbA = min(64, s1A - s0A), cbB = min(64, s1B - s0B);
        floatx4 accA = {0.f, 0.f, 0.f, 0.f};
        floatx4 accB = {0.f, 0.f, 0.f, 0.f};
        {   // unconditional first 16 slots for both nodes: 8 loads in flight, then consume
            half4v vA[4], vB[4];
            LOAD4(ef[j2], 0, vA);
            LOAD4(ef[j2 + 1], 0, vB);
            ACC4(vA, accA);
            ACC4(vB, accB);
        }
        // wave-uniform extensions (deg>16: P~0.43)
        if (cbA > 16) {
            half4v v0[4];
            LOAD4(ef[j2], 16, v0);
            ACC4(v0, accA);
            if (cbA > 32) { half4v v1[4]; LOAD4(ef[j2], 32, v1); ACC4(v1, accA); }
            if (cbA > 48) { half4v v2[4]; LOAD4(ef[j2], 48, v2); ACC4(v2, accA); }
        }
        if (cbB > 16) {
            half4v v0[4];
            LOAD4(ef[j2 + 1], 16, v0);
            ACC4(v0, accB);
            if (cbB > 32) { half4v v1[4]; LOAD4(ef[j2 + 1], 32, v1); ACC4(v1, accB); }
            if (cbB > 48) { half4v v2[4]; LOAD4(ef[j2 + 1], 48, v2); ACC4(v2, accB); }
        }
        // rare deg>64 tails
        for (int base_ = s0A + 64; base_ < s1A; base_ += 64) {
            int cb = min(64, s1A - base_);
            int ei = (lane < cb) ? csr_src[base_ + lane] : n;
            for (int i0 = 0; i0 < cb; i0 += 16) {
                half4v vt[4];
                LOAD4(ei, i0, vt);
                ACC4(vt, accA);
            }
        }
        for (int base_ = s0B + 64; base_ < s1B; base_ += 64) {
            int cb = min(64, s1B - base_);
            int ei = (lane < cb) ? csr_src[base_ + lane] : n;
            for (int i0 = 0; i0 < cb; i0 += 16) {
                half4v vt[4];
                LOAD4(ei, i0, vt);
                ACC4(vt, accB);
            }
        }
        // cross-quad reduce: quads hold different row-slots
        accA.x += __shfl_xor(accA.x, 16); accA.y += __shfl_xor(accA.y, 16);
        accA.z += __shfl_xor(accA.z, 16); accA.w += __shfl_xor(accA.w, 16);
        accA.x += __shfl_xor(accA.x, 32); accA.y += __shfl_xor(accA.y, 32);
        accA.z += __shfl_xor(accA.z, 32); accA.w += __shfl_xor(accA.w, 32);
        accB.x += __shfl_xor(accB.x, 16); accB.y += __shfl_xor(accB.y, 16);
        accB.z += __shfl_xor(accB.z, 16); accB.w += __shfl_xor(accB.w, 16);
        accB.x += __shfl_xor(accB.x, 32); accB.y += __shfl_xor(accB.y, 32);
        accB.z += __shfl_xor(accB.z, 32); accB.w += __shfl_xor(accB.w, 32);
        if (quad == 0) {
            half4v hw;
            hw[0] = (_Float16)(accA.x * idgA);
            hw[1] = (_Float16)(accA.y * idgA);
            hw[2] = (_Float16)(accA.z * idgA);
            hw[3] = (_Float16)(accA.w * idgA);
            *(half4v*)(my_in + j2 * PADK + m16 * 4) = hw;
        } else if (quad == 1) {
            half4v hw;
            hw[0] = (_Float16)(accB.x * idgB);
            hw[1] = (_Float16)(accB.y * idgB);
            hw[2] = (_Float16)(accB.z * idgB);
            hw[3] = (_Float16)(accB.w * idgB);
            *(half4v*)(my_in + (j2 + 1) * PADK + m16 * 4) = hw;
        }
    }
    half8 afrag[4];
    const _Float16* abase = my_in + m16 * PADK + quad * 8;
#pragma unroll
    for (int ks = 0; ks < 4; ks++) afrag[ks] = *(const half8*)(abase + ks * 32);
    floatx4 accv[4];
#pragma unroll
    for (int nt = 0; nt < 4; nt++) {
        accv[nt].x = 0.f; accv[nt].y = 0.f; accv[nt].z = 0.f; accv[nt].w = 0.f;
    }
#pragma unroll
    for (int nt = 0; nt < 4; nt++) {
        const _Float16* bbase = w_lds + (nt * 16 + m16) * PADK + quad * 8;
#pragma unroll
        for (int ks = 0; ks < 4; ks++) {
            half8 bfrag = *(const half8*)(bbase + ks * 32);
            accv[nt] = __builtin_amdgcn_mfma_f32_16x16x32_f16(afrag[ks], bfrag, accv[nt], 0, 0, 0);
        }
    }
#pragma unroll
    for (int nt = 0; nt < 4; nt++) {
#pragma unroll
        for (int r = 0; r < 4; r++) {
            int node = nd0 + quad * 4 + r;
            if (node < n) {
                float v = fmaxf(accv[nt][r] + bias[nt], 0.0f);
                hout[(size_t)node * 64 + nt * 16 + m16] = __float2half(v);
            }
        }
    }
}

// ---------------- SAGE layer 3 + fused global-mean-pool epilogue (R3-verbatim) ----------------
__global__ __launch_bounds__(512, 4) void gnn_sage_pool(const __half* __restrict__ hin,
                                                        const int* __restrict__ row_ptr,
                                                        const int* __restrict__ csr_src,
                                                        const float* __restrict__ inv_deg,
                                                        const float* __restrict__ Wl,
                                                        const float* __restrict__ bl,
                                                        const float* __restrict__ Wr,
                                                        const int* __restrict__ batch,
                                                        float* __restrict__ gsum, int n) {
    __shared__ _Float16 w_lds[64 * PADK];
    __shared__ _Float16 in_lds[WPB][16 * PADK];
    int tid = threadIdx.x, lane = tid & 63, wv = tid >> 6;
    for (int i = tid; i < 64 * 64; i += 512) {
        int k = i >> 6, nn = i & 63;
        w_lds[nn * PADK + k] = (_Float16)Wl[i];
        w_lds[nn * PADK + 64 + k] = (_Float16)Wr[i];
    }
    __syncthreads();
    int ngroups = (n + 15) >> 4;
    int g = blockIdx.x * WPB + wv;
    if (g >= ngroups) return;
    int m16 = lane & 15, quad = lane >> 4;
    int hf = lane >> 5, col = lane & 31;
    float bias[4];
#pragma unroll
    for (int nt = 0; nt < 4; nt++) bias[nt] = bl[nt * 16 + m16];
    _Float16* my_in = in_lds[wv];
    const unsigned* hin32 = (const unsigned*)hin;
    const half4v* hin4v = (const half4v*)hin;
    int nd0 = g << 4;
    int nclamp = n - 1 - nd0;  // >= 0
    int idx = nd0 + lane;
    int rr = (lane <= 16) ? row_ptr[min(idx, n)] : 0;
    float ig = (lane < 16) ? inv_deg[min(idx, n - 1)] : 0.0f;

#pragma unroll
    for (int jp = 0; jp < 8; jp++) {
        int j2 = jp << 1;
        int nd = nd0 + min(j2 + hf, nclamp);
        unsigned u = hin32[(size_t)nd * 32 + col];
        ((unsigned*)(my_in + (j2 + hf) * PADK + 64))[col] = u;
    }

    int ef[16];
#pragma unroll
    for (int j = 0; j < 16; j++) {
        int jj = min(j, nclamp);
        int s0 = __shfl(rr, jj), s1 = __shfl(rr, jj + 1);
        int cb = min(64, s1 - s0);
        ef[j] = (lane < cb) ? csr_src[s0 + lane] : n;
    }

#pragma unroll
    for (int jp = 0; jp < 8; jp++) {
        int j2 = jp << 1;
        int jjA = min(j2, nclamp), jjB = min(j2 + 1, nclamp);
        int s0A = __shfl(rr, jjA), s1A = __shfl(rr, jjA + 1);
        int s0B = __shfl(rr, jjB), s1B = __shfl(rr, jjB + 1);
        float idgA = __shfl(ig, jjA), idgB = __shfl(ig, jjB);
        int cbA = min(64, s1A - s0A), cbB = min(64, s1B - s0B);
        floatx4 accA = {0.f, 0.f, 0.f, 0.f};
        floatx4 accB = {0.f, 0.f, 0.f, 0.f};
        {
            half4v vA[4], vB[4];
            LOAD4(ef[j2], 0, vA);
            LOAD4(ef[j2 + 1], 0, vB);
            ACC4(vA, accA);
            ACC4(vB, accB);
        }
        if (cbA > 16) {
            half4v v0[4];
            LOAD4(ef[j2], 16, v0);
            ACC4(v0, accA);
            if (cbA > 32) { half4v v1[4]; LOAD4(ef[j2], 32, v1); ACC4(v1, accA); }
            if (cbA > 48) { half4v v2[4]; LOAD4(ef[j2], 48, v2); ACC4(v2, accA); }
        }
        if (cbB > 16) {
            half4v v0[4];
            LOAD4(ef[j2 + 1], 16, v0);
            ACC4(v0, accB);
            if (cbB > 32) { half4v v1[4]; LOAD4(ef[j2 + 1], 32, v1); ACC4(v1, accB); }
            if (cbB > 48) { half4v v2[4]; LOAD4(ef[j2 + 1], 48, v2); ACC4(v2, accB); }
        }
        for (int base_ = s0A + 64; base_ < s1A; base_ += 64) {
            int cb = min(64, s1A - base_);
            int ei = (lane < cb) ? csr_src[base_ + lane] : n;
            for (int i0 = 0; i0 < cb; i0 += 16) {
                half4v vt[4];
                LOAD4(ei, i0, vt);
                ACC4(vt, accA);
            }
        }
        for (int base_ = s0B + 64; base_ < s1B; base_ += 64) {
            int cb = min(64, s1B - base_);
            int ei = (lane < cb) ? csr_src[base_ + lane] : n;
            for (int i0 = 0; i0 < cb; i0 += 16) {
                half4v vt[4];
                LOAD4(ei, i0, vt);
                ACC4(vt, accB);
            }
        }
        accA.x += __shfl_xor(accA.x, 16); accA.y += __shfl_xor(accA.y, 16);
        accA.z += __shfl_xor(accA.z, 16); accA.w += __shfl_xor(accA.w, 16);
        accA.x += __shfl_xor(accA.x, 32); accA.y += __shfl_xor(accA.y, 32);
        accA.z += __shfl_xor(accA.z, 32); accA.w += __shfl_xor(accA.w, 32);
        accB.x += __shfl_xor(accB.x, 16); accB.y += __shfl_xor(accB.y, 16);
        accB.z += __shfl_xor(accB.z, 16); accB.w += __shfl_xor(accB.w, 16);
        accB.x += __shfl_xor(accB.x, 32); accB.y += __shfl_xor(accB.y, 32);
        accB.z += __shfl_xor(accB.z, 32); accB.w += __shfl_xor(accB.w, 32);
        if (quad == 0) {
            half4v hw;
            hw[0] = (_Float16)(accA.x * idgA);
            hw[1] = (_Float16)(accA.y * idgA);
            hw[2] = (_Float16)(accA.z * idgA);
            hw[3] = (_Float16)(accA.w * idgA);
            *(half4v*)(my_in + j2 * PADK + m16 * 4) = hw;
        } else if (quad == 1) {
            half4v hw;
            hw[0] = (_Float16)(accB.x * idgB);
            hw[1] = (_Float16)(accB.y * idgB);
            hw[2] = (_Float16)(accB.z * idgB);
            hw[3] = (_Float16)(accB.w * idgB);
            *(half4v*)(my_in + (j2 + 1) * PADK + m16 * 4) = hw;
        }
    }
    half8 afrag[4];
    const _Float16* abase = my_in + m16 * PADK + quad * 8;
#pragma unroll
    for (int ks = 0; ks < 4; ks++) afrag[ks] = *(const half8*)(abase + ks * 32);
    floatx4 accv[4];
#pragma unroll
    for (int nt = 0; nt < 4; nt++) {
        accv[nt].x = 0.f; accv[nt].y = 0.f; accv[nt].z = 0.f; accv[nt].w = 0.f;
    }
#pragma unroll
    for (int nt = 0; nt < 4; nt++) {
        const _Float16* bbase = w_lds + (nt * 16 + m16) * PADK + quad * 8;
#pragma unroll
        for (int ks = 0; ks < 4; ks++) {
            half8 bfrag = *(const half8*)(bbase + ks * 32);
            accv[nt] = __builtin_amdgcn_mfma_f32_16x16x32_f16(afrag[ks], bfrag, accv[nt], 0, 0, 0);
        }
    }
    // ---- fused pool epilogue ----
    int bFirst = batch[nd0];
    int bLast = batch[min(nd0 + 15, n - 1)];
    if (bFirst == bLast && nd0 + 15 < n) {
#pragma unroll
        for (int nt = 0; nt < 4; nt++) {
            float s = fmaxf(accv[nt][0] + bias[nt], 0.0f) + fmaxf(accv[nt][1] + bias[nt], 0.0f) +
                      fmaxf(accv[nt][2] + bias[nt], 0.0f) + fmaxf(accv[nt][3] + bias[nt], 0.0f);
            s += __shfl_xor(s, 16);
            s += __shfl_xor(s, 32);
            if (quad == 0) atomicAdd(&gsum[bFirst * 64 + nt * 16 + m16], s);
        }
    } else {
#pragma unroll
        for (int nt = 0; nt < 4; nt++) {
#pragma unroll
            for (int r = 0; r < 4; r++) {
                int node = nd0 + quad * 4 + r;
                if (node < n) {
                    int bg = batch[node];
                    float v = fmaxf(accv[nt][r] + bias[nt], 0.0f);
                    atomicAdd(&gsum[bg * 64 + nt * 16 + m16], v);
                }
            }
        }
    }
}

// ---------------- head (1024 threads) ----------------
__global__ __launch_bounds__(1024) void gnn_head(const float* __restrict__ gsum,
                                                 const float* __restrict__ gcnt,
                                                 const float* __restrict__ l0W,
                                                 const float* __restrict__ l0b,
                                                 const float* __restrict__ outW,
                                                 const float* __restrict__ outb,
                                                 float* __restrict__ out, int G, int OUT) {
    __shared__ float gm[64 * 64];
    __shared__ float t2[64 * 64];
    int tid = threadIdx.x;
    for (int i = tid; i < G * 64; i += 1024) {
        int r = i >> 6;
        gm[i] = gsum[i] / fmaxf(gcnt[r], 1.0f);
    }
    __syncthreads();
    for (int i = tid; i < G * 64; i += 1024) {
        int r = i >> 6, c = i & 63;
        float s = l0b[c];
#pragma unroll 8
        for (int k = 0; k < 64; k++) s += gm[(r << 6) + k] * l0W[(k << 6) + c];
        t2[i] = fmaxf(s, 0.0f);
    }
    __syncthreads();
    for (int i = tid; i < G * OUT; i += 1024) {
        int r = i / OUT, c = i - r * OUT;
        float s = outb[c];
#pragma unroll 8
        for (int k = 0; k < 64; k++) s += t2[(r << 6) + k] * outW[k * OUT + c];
        out[i] = s;
    }
}

extern "C" void kernel_launch(void* const* d_in, const int* in_sizes, int n_in,
                              void* d_out, int out_size, void* d_ws, size_t ws_size,
                              hipStream_t stream) {
    const float* x = (const float*)d_in[0];
    const int* ei = (const int*)d_in[1];
    const int* batch = (const int*)d_in[2];
    const float* Wl[3] = {(const float*)d_in[3], (const float*)d_in[6], (const float*)d_in[9]};
    const float* bl[3] = {(const float*)d_in[4], (const float*)d_in[7], (const float*)d_in[10]};
    const float* Wr[3] = {(const float*)d_in[5], (const float*)d_in[8], (const float*)d_in[11]};
    const float* l0W = (const float*)d_in[12];
    const float* l0b = (const float*)d_in[13];
    const float* outW = (const float*)d_in[14];
    const float* outb = (const float*)d_in[15];

    int N = in_sizes[2];
    int E = in_sizes[1] / 2;
    int OUT = 10;
    int G = out_size / OUT;
    const int* src = ei;
    const int* dst = ei + E;
    int NBKT = (N + BNODES - 1) >> BSH;

    char* ws = (char*)d_ws;
    size_t off = 0;
    auto alloc = [&](size_t b) -> char* {
        char* p = ws + off;
        off = (off + b + 255) & ~(size_t)255;
        return p;
    };
    int* row_ptr = (int*)alloc((size_t)(N + 1) * 4);
    int* csr_src = (int*)alloc((size_t)E * 4);
    float* inv_deg = (float*)alloc((size_t)N * 4);
    // contiguous zero region: bkt_cnt | gcnt | gsum (one memset)
    size_t zoff = off;
    int* bkt_cnt = (int*)alloc((size_t)NBKT * 4);
    float* gcnt = (float*)alloc((size_t)G * 4);
    float* gsum = (float*)alloc((size_t)G * 64 * 4);
    size_t zlen = off - zoff;
    int* bkt_base = (int*)alloc((size_t)(NBKT + 1) * 4);
    int* hist_all = (int*)alloc((size_t)HIST_BLOCKS * HSTRIDE * 4);
    int* blk_base_all = (int*)alloc((size_t)HIST_BLOCKS * HSTRIDE * 4);
    unsigned int* pairs = (unsigned int*)alloc((size_t)E * 4);
    __half* x16 = (__half*)alloc((size_t)(N + 1) * 64 * 2);  // +1 sentinel row
    __half* hA = (__half*)alloc((size_t)(N + 1) * 64 * 2);
    __half* hB = (__half*)alloc((size_t)(N + 1) * 64 * 2);

    hipMemsetAsync(ws + zoff, 0, zlen, stream);

    int n4 = N * 64 / 4;
    int pre_blocks = HIST_BLOCKS + (n4 + 255) / 256;
    gnn_pre<<<pre_blocks, 256, 0, stream>>>(dst, bkt_cnt, NBKT, E, batch, gcnt, N,
                                            (const float4*)x, (ushort4*)x16, n4,
                                            x16, hA, hB, hist_all);
    gnn_scan2<<<NBKT, 256, 0, stream>>>(hist_all, bkt_cnt, bkt_base, row_ptr,
                                        blk_base_all, NBKT, N);
    gnn_bkt_scatter<<<SC_BLOCKS, 256, 0, stream>>>(src, dst, hist_all, blk_base_all,
                                                   pairs, E, NBKT);
    gnn_bkt_csr<<<NBKT, 256, 0, stream>>>(pairs, bkt_base, row_ptr, inv_deg, csr_src, N);

    int ngroups = (N + 15) >> 4;
    int sage_blocks = (ngroups + WPB - 1) / WPB;
    gnn_sage<<<sage_blocks, 512, 0, stream>>>(x16, hA, row_ptr, csr_src, inv_deg,
                                              Wl[0], bl[0], Wr[0], N);
    gnn_sage<<<sage_blocks, 512, 0, stream>>>(hA, hB, row_ptr, csr_src, inv_deg,
                                              Wl[1], bl[1], Wr[1], N);
    gnn_sage_pool<<<sage_blocks, 512, 0, stream>>>(hB, row_ptr, csr_src, inv_deg,
                                                   Wl[2], bl[2], Wr[2], batch, gsum, N);

    gnn_head<<<1, 1024, 0, stream>>>(gsum, gcnt, l0W, l0b, outW, outb, (float*)d_out, G, OUT);
}

// Round 9
// 289.291 us; speedup vs baseline: 1.0620x; 1.0620x over previous
//
#include <hip/hip_runtime.h>
#include <hip/hip_fp16.h>

#define WPB 8     // waves per sage block (512 threads)
#define PADK 136  // f16 elems per LDS row: 128 + 8 pad (16B-aligned rows)
#define BSH 8     // bucket shift: 256 nodes per bucket
#define BNODES 256
#define SC_BLOCKS 256   // MUST equal HIST_BLOCKS (chunk mapping shared)
#define HIST_BLOCKS 256
#define HSTRIDE 512     // padded bucket stride in hist_all / blk_base_all
#define PSTAGE 12288    // csr: LDS-staged pairs capacity (48KB)

typedef _Float16 half8 __attribute__((ext_vector_type(8)));
typedef _Float16 half4v __attribute__((ext_vector_type(4)));
typedef float floatx4 __attribute__((ext_vector_type(4)));

// ---------------- pre: hist (blocks 0..255, persisted per-block) + x->f16 cvt (rest) ----------------
// Edge chunk mapping (int4 when E%4==0) MUST match gnn_bkt_scatter exactly.
__global__ __launch_bounds__(256) void gnn_pre(const int* __restrict__ dst,
                                               int* __restrict__ bkt_cnt, int nbkt, int E,
                                               const int* __restrict__ batch,
                                               float* __restrict__ gcnt, int N,
                                               const float4* __restrict__ xin,
                                               ushort4* __restrict__ x16o, int n4,
                                               __half* __restrict__ x16,
                                               __half* __restrict__ hA,
                                               __half* __restrict__ hB,
                                               int* __restrict__ hist_all) {
    int tid = threadIdx.x;
    if (blockIdx.x < HIST_BLOCKS) {
        __shared__ int h[512];
        __shared__ int gb[64];
        for (int i = tid; i < nbkt; i += 256) h[i] = 0;
        if (tid < 64) gb[tid] = 0;
        __syncthreads();
        const int stride = HIST_BLOCKS * 256;
        if ((E & 3) == 0) {
            const int4* dst4 = (const int4*)dst;
            int E4 = E >> 2;
            for (int e = blockIdx.x * 256 + tid; e < E4; e += stride) {
                int4 d = dst4[e];
                atomicAdd(&h[d.x >> BSH], 1);
                atomicAdd(&h[d.y >> BSH], 1);
                atomicAdd(&h[d.z >> BSH], 1);
                atomicAdd(&h[d.w >> BSH], 1);
            }
        } else {
            for (int e = blockIdx.x * 256 + tid; e < E; e += stride)
                atomicAdd(&h[dst[e] >> BSH], 1);
        }
        for (int i = blockIdx.x * 256 + tid; i < N; i += stride)
            atomicAdd(&gb[batch[i]], 1);
        __syncthreads();
        for (int i = tid; i < nbkt; i += 256) {
            int v = h[i];
            hist_all[blockIdx.x * HSTRIDE + i] = v;  // persist per-block chunk histogram
            if (v) atomicAdd(&bkt_cnt[i], v);
        }
        if (tid < 64) {
            int v = gb[tid];
            if (v) atomicAdd(&gcnt[tid], (float)v);
        }
        if (blockIdx.x == 0 && tid < 64) {  // zero sentinel row N of x16, hA, hB
            x16[(size_t)N * 64 + tid] = __ushort_as_half((unsigned short)0);
            hA[(size_t)N * 64 + tid] = __ushort_as_half((unsigned short)0);
            hB[(size_t)N * 64 + tid] = __ushort_as_half((unsigned short)0);
        }
    } else {
        int i = (blockIdx.x - HIST_BLOCKS) * 256 + tid;
        if (i < n4) {
            float4 f = xin[i];
            ushort4 o;
            o.x = __half_as_ushort(__float2half(f.x));
            o.y = __half_as_ushort(__float2half(f.y));
            o.z = __half_as_ushort(__float2half(f.z));
            o.w = __half_as_ushort(__float2half(f.w));
            x16o[i] = o;
        }
    }
}

// ---------------- scan2: per-bucket exclusive scan over blocks -> exact scatter bases.
// Also computes bkt_base[b] per block (reduction of bkt_cnt[<b]) — no separate scan kernel.
__global__ __launch_bounds__(256) void gnn_scan2(const int* __restrict__ hist_all,
                                                 const int* __restrict__ bkt_cnt,
                                                 int* __restrict__ bkt_base,
                                                 int* __restrict__ row_ptr,
                                                 int* __restrict__ blk_base_all,
                                                 int nbkt, int N) {
    int b = blockIdx.x;
    int t = threadIdx.x, lane = t & 63, wv = t >> 6;
    __shared__ int wsum[4];
    __shared__ int red[4];
    // partial sum of bkt_cnt[0..b-1]
    int part = 0;
    for (int i = t; i < b; i += 256) part += bkt_cnt[i];
#pragma unroll
    for (int off = 1; off < 64; off <<= 1) part += __shfl_xor(part, off);
    if (lane == 0) red[wv] = part;
    // per-chunk scan of this bucket's histogram column
    int v = hist_all[t * HSTRIDE + b];
    int x = v;
#pragma unroll
    for (int off = 1; off < 64; off <<= 1) {
        int y = __shfl_up(x, off);
        if (lane >= off) x += y;
    }
    if (lane == 63) wsum[wv] = x;
    __syncthreads();
    int base = red[0] + red[1] + red[2] + red[3];
    int wexcl = 0;
    for (int w = 0; w < wv; w++) wexcl += wsum[w];
    blk_base_all[t * HSTRIDE + b] = base + wexcl + (x - v);
    if (t == 0) {
        bkt_base[b] = base;
        if (b == nbkt - 1) {
            int tot = base + bkt_cnt[b];
            bkt_base[nbkt] = tot;
            row_ptr[N] = tot;
        }
    }
}

// ---------------- deterministic scatter (R6-direct: LDS cursors, random 4B writes —
// pairs is 6.4MB => ~800KB/XCD, L2 absorbs and line-aggregates; counting-sort regressed) ----
__global__ __launch_bounds__(256) void gnn_bkt_scatter(const int* __restrict__ src,
                                                       const int* __restrict__ dst,
                                                       const int* __restrict__ blk_base_all,
                                                       unsigned int* __restrict__ pairs,
                                                       int E, int nbkt) {
    __shared__ int cur[512];
    int tid = threadIdx.x;
    for (int i = tid; i < nbkt; i += 256) cur[i] = blk_base_all[blockIdx.x * HSTRIDE + i];
    __syncthreads();
    const int stride = SC_BLOCKS * 256;  // SAME chunk mapping as gnn_pre's histogram
    if ((E & 3) == 0) {
        const int4* dst4 = (const int4*)dst;
        const int4* src4 = (const int4*)src;
        int E4 = E >> 2;
        for (int e = blockIdx.x * 256 + tid; e < E4; e += stride) {
            int4 d = dst4[e];
            int4 s = src4[e];
            int p0 = atomicAdd(&cur[d.x >> BSH], 1);
            pairs[p0] = (unsigned int)s.x | ((unsigned int)(d.x & (BNODES - 1)) << 24);
            int p1 = atomicAdd(&cur[d.y >> BSH], 1);
            pairs[p1] = (unsigned int)s.y | ((unsigned int)(d.y & (BNODES - 1)) << 24);
            int p2 = atomicAdd(&cur[d.z >> BSH], 1);
            pairs[p2] = (unsigned int)s.z | ((unsigned int)(d.z & (BNODES - 1)) << 24);
            int p3 = atomicAdd(&cur[d.w >> BSH], 1);
            pairs[p3] = (unsigned int)s.w | ((unsigned int)(d.w & (BNODES - 1)) << 24);
        }
    } else {
        for (int e = blockIdx.x * 256 + tid; e < E; e += stride) {
            int d = dst[e];
            int b = d >> BSH;
            int p = atomicAdd(&cur[b], 1);  // LDS atomic only
            pairs[p] = (unsigned int)src[e] | ((unsigned int)(d & (BNODES - 1)) << 24);
        }
    }
}

// ---------------- per-bucket CSR finalize (pairs staged in LDS once, both passes local) ----
__global__ __launch_bounds__(256) void gnn_bkt_csr(const unsigned int* __restrict__ pairs,
                                                   const int* __restrict__ bkt_base,
                                                   int* __restrict__ row_ptr,
                                                   float* __restrict__ inv_deg,
                                                   int* __restrict__ csr_src, int N) {
    __shared__ int hist[BNODES];
    __shared__ int excl[BNODES];
    __shared__ int cur[BNODES];
    __shared__ unsigned int pstage[PSTAGE];
    int b = blockIdx.x;
    int base = bkt_base[b];
    int cnt = bkt_base[b + 1] - base;
    int nd0 = b << BSH;
    int tid = threadIdx.x;
    hist[tid] = 0;
    __syncthreads();
    int scnt = min(cnt, PSTAGE);
    for (int i = tid; i < scnt; i += 256) {
        unsigned int u = pairs[base + i];
        pstage[i] = u;
        atomicAdd(&hist[u >> 24], 1);
    }
    for (int i = scnt + tid; i < cnt; i += 256)  // overflow fallback (P~0)
        atomicAdd(&hist[pairs[base + i] >> 24], 1);
    __syncthreads();
    if (tid < 64) {
        int carry = 0;
#pragma unroll
        for (int c = 0; c < BNODES; c += 64) {
            int v = hist[c + tid];
            int x = v;
#pragma unroll
            for (int off = 1; off < 64; off <<= 1) {
                int y = __shfl_up(x, off);
                if (tid >= off) x += y;
            }
            excl[c + tid] = carry + (x - v);
            carry += __shfl(x, 63);
        }
    }
    __syncthreads();
    {
        int node = nd0 + tid;
        if (node < N) {
            row_ptr[node] = base + excl[tid];
            int d = hist[tid];
            inv_deg[node] = 1.0f / (float)(d > 1 ? d : 1);
        }
        cur[tid] = excl[tid];
    }
    __syncthreads();
    for (int i = tid; i < scnt; i += 256) {
        unsigned int u = pstage[i];
        int pos = atomicAdd(&cur[u >> 24], 1);
        csr_src[base + pos] = (int)(u & 0xFFFFFFu);
    }
    for (int i = scnt + tid; i < cnt; i += 256) {
        unsigned int u = pairs[base + i];
        int pos = atomicAdd(&cur[u >> 24], 1);
        csr_src[base + pos] = (int)(u & 0xFFFFFFu);
    }
}

// load batch of one 16-slot chunk (4 dwordx2 loads, 4 rows each) into vArr
#define LOAD4(eReg, c0, vArr)                                  \
    _Pragma("unroll") for (int c_ = 0; c_ < 4; c_++) {         \
        int sj_ = __shfl(eReg, (c0) + c_ * 4 + quad);          \
        vArr[c_] = hin4v[(size_t)sj_ * 16 + m16];              \
    }
// consume batch
#define ACC4(vArr, accum)                                      \
    _Pragma("unroll") for (int c_ = 0; c_ < 4; c_++) {         \
        accum.x += (float)vArr[c_][0];                         \
        accum.y += (float)vArr[c_][1];                         \
        accum.z += (float)vArr[c_][2];                         \
        accum.w += (float)vArr[c_][3];                         \
    }

// ---------------- SAGE layer (R3-verbatim: proven 51us/layer — near random-line service floor) ----
__global__ __launch_bounds__(512, 4) void gnn_sage(const __half* __restrict__ hin,
                                                   __half* __restrict__ hout,
                                                   const int* __restrict__ row_ptr,
                                                   const int* __restrict__ csr_src,
                                                   const float* __restrict__ inv_deg,
                                                   const float* __restrict__ Wl,
                                                   const float* __restrict__ bl,
                                                   const float* __restrict__ Wr, int n) {
    __shared__ _Float16 w_lds[64 * PADK];
    __shared__ _Float16 in_lds[WPB][16 * PADK];
    int tid = threadIdx.x, lane = tid & 63, wv = tid >> 6;
    for (int i = tid; i < 64 * 64; i += 512) {
        int k = i >> 6, nn = i & 63;
        w_lds[nn * PADK + k] = (_Float16)Wl[i];
        w_lds[nn * PADK + 64 + k] = (_Float16)Wr[i];
    }
    __syncthreads();
    int ngroups = (n + 15) >> 4;
    int g = blockIdx.x * WPB + wv;
    if (g >= ngroups) return;
    int m16 = lane & 15, quad = lane >> 4;
    int hf = lane >> 5, col = lane & 31;
    float bias[4];
#pragma unroll
    for (int nt = 0; nt < 4; nt++) bias[nt] = bl[nt * 16 + m16];
    _Float16* my_in = in_lds[wv];
    const unsigned* hin32 = (const unsigned*)hin;
    const half4v* hin4v = (const half4v*)hin;
    int nd0 = g << 4;
    int nclamp = n - 1 - nd0;  // >= 0
    int idx = nd0 + lane;
    int rr = (lane <= 16) ? row_ptr[min(idx, n)] : 0;
    float ig = (lane < 16) ? inv_deg[min(idx, n - 1)] : 0.0f;

    // root rows -> LDS cols 64..127 (dword copies, 2 rows per load)
#pragma unroll
    for (int jp = 0; jp < 8; jp++) {
        int j2 = jp << 1;
        int nd = nd0 + min(j2 + hf, nclamp);
        unsigned u = hin32[(size_t)nd * 32 + col];
        ((unsigned*)(my_in + (j2 + hf) * PADK + 64))[col] = u;
    }

    // first-64 neighbor indices for all 16 nodes, hoisted (sentinel n beyond degree)
    int ef[16];
#pragma unroll
    for (int j = 0; j < 16; j++) {
        int jj = min(j, nclamp);
        int s0 = __shfl(rr, jj), s1 = __shfl(rr, jj + 1);
        int cb = min(64, s1 - s0);
        ef[j] = (lane < cb) ? csr_src[s0 + lane] : n;
    }

#pragma unroll
    for (int jp = 0; jp < 8; jp++) {
        int j2 = jp << 1;
        int jjA = min(j2, nclamp), jjB = min(j2 + 1, nclamp);
        int s0A = __shfl(rr, jjA), s1A = __shfl(rr, jjA + 1);
        int s0B = __shfl(rr, jjB), s1B = __shfl(rr, jjB + 1);
        float idgA = __shfl(ig, jjA), idgB = __shfl(ig, jjB);
        int cbA = min(64, s1A - s0A), cbB = min(64, s1B - s0B);
        floatx4 accA = {0.f, 0.f, 0.f, 0.f};
        floatx4 accB = {0.f, 0.f, 0.f, 0.f};
        {   // unconditional first 16 slots for both nodes: 8 loads in flight, then consume
            half4v vA[4], vB[4];
            LOAD4(ef[j2], 0, vA);
            LOAD4(ef[j2 + 1], 0, vB);
            ACC4(vA, accA);
            ACC4(vB, accB);
        }
        // wave-uniform extensions (deg>16: P~0.43)
        if (cbA > 16) {
            half4v v0[4];
            LOAD4(ef[j2], 16, v0);
            ACC4(v0, accA);
            if (cbA > 32) { half4v v1[4]; LOAD4(ef[j2], 32, v1); ACC4(v1, accA); }
            if (cbA > 48) { half4v v2[4]; LOAD4(ef[j2], 48, v2); ACC4(v2, accA); }
        }
        if (cbB > 16) {
            half4v v0[4];
            LOAD4(ef[j2 + 1], 16, v0);
            ACC4(v0, accB);
            if (cbB > 32) { half4v v1[4]; LOAD4(ef[j2 + 1], 32, v1); ACC4(v1, accB); }
            if (cbB > 48) { half4v v2[4]; LOAD4(ef[j2 + 1], 48, v2); ACC4(v2, accB); }
        }
        // rare deg>64 tails
        for (int base_ = s0A + 64; base_ < s1A; base_ += 64) {
            int cb = min(64, s1A - base_);
            int ei = (lane < cb) ? csr_src[base_ + lane] : n;
            for (int i0 = 0; i0 < cb; i0 += 16) {
                half4v vt[4];
                LOAD4(ei, i0, vt);
                ACC4(vt, accA);
            }
        }
        for (int base_ = s0B + 64; base_ < s1B; base_ += 64) {
            int cb = min(64, s1B - base_);
            int ei = (lane < cb) ? csr_src[base_ + lane] : n;
            for (int i0 = 0; i0 < cb; i0 += 16) {
                half4v vt[4];
                LOAD4(ei, i0, vt);
                ACC4(vt, accB);
            }
        }
        // cross-quad reduce: quads hold different row-slots
        accA.x += __shfl_xor(accA.x, 16); accA.y += __shfl_xor(accA.y, 16);
        accA.z += __shfl_xor(accA.z, 16); accA.w += __shfl_xor(accA.w, 16);
        accA.x += __shfl_xor(accA.x, 32); accA.y += __shfl_xor(accA.y, 32);
        accA.z += __shfl_xor(accA.z, 32); accA.w += __shfl_xor(accA.w, 32);
        accB.x += __shfl_xor(accB.x, 16); accB.y += __shfl_xor(accB.y, 16);
        accB.z += __shfl_xor(accB.z, 16); accB.w += __shfl_xor(accB.w, 16);
        accB.x += __shfl_xor(accB.x, 32); accB.y += __shfl_xor(accB.y, 32);
        accB.z += __shfl_xor(accB.z, 32); accB.w += __shfl_xor(accB.w, 32);
        if (quad == 0) {
            half4v hw;
            hw[0] = (_Float16)(accA.x * idgA);
            hw[1] = (_Float16)(accA.y * idgA);
            hw[2] = (_Float16)(accA.z * idgA);
            hw[3] = (_Float16)(accA.w * idgA);
            *(half4v*)(my_in + j2 * PADK + m16 * 4) = hw;
        } else if (quad == 1) {
            half4v hw;
            hw[0] = (_Float16)(accB.x * idgB);
            hw[1] = (_Float16)(accB.y * idgB);
            hw[2] = (_Float16)(accB.z * idgB);
            hw[3] = (_Float16)(accB.w * idgB);
            *(half4v*)(my_in + (j2 + 1) * PADK + m16 * 4) = hw;
        }
    }
    half8 afrag[4];
    const _Float16* abase = my_in + m16 * PADK + quad * 8;
#pragma unroll
    for (int ks = 0; ks < 4; ks++) afrag[ks] = *(const half8*)(abase + ks * 32);
    floatx4 accv[4];
#pragma unroll
    for (int nt = 0; nt < 4; nt++) {
        accv[nt].x = 0.f; accv[nt].y = 0.f; accv[nt].z = 0.f; accv[nt].w = 0.f;
    }
#pragma unroll
    for (int nt = 0; nt < 4; nt++) {
        const _Float16* bbase = w_lds + (nt * 16 + m16) * PADK + quad * 8;
#pragma unroll
        for (int ks = 0; ks < 4; ks++) {
            half8 bfrag = *(const half8*)(bbase + ks * 32);
            accv[nt] = __builtin_amdgcn_mfma_f32_16x16x32_f16(afrag[ks], bfrag, accv[nt], 0, 0, 0);
        }
    }
#pragma unroll
    for (int nt = 0; nt < 4; nt++) {
#pragma unroll
        for (int r = 0; r < 4; r++) {
            int node = nd0 + quad * 4 + r;
            if (node < n) {
                float v = fmaxf(accv[nt][r] + bias[nt], 0.0f);
                hout[(size_t)node * 64 + nt * 16 + m16] = __float2half(v);
            }
        }
    }
}

// ---------------- SAGE layer 3 + fused global-mean-pool epilogue (R3-verbatim) ----------------
__global__ __launch_bounds__(512, 4) void gnn_sage_pool(const __half* __restrict__ hin,
                                                        const int* __restrict__ row_ptr,
                                                        const int* __restrict__ csr_src,
                                                        const float* __restrict__ inv_deg,
                                                        const float* __restrict__ Wl,
                                                        const float* __restrict__ bl,
                                                        const float* __restrict__ Wr,
                                                        const int* __restrict__ batch,
                                                        float* __restrict__ gsum, int n) {
    __shared__ _Float16 w_lds[64 * PADK];
    __shared__ _Float16 in_lds[WPB][16 * PADK];
    int tid = threadIdx.x, lane = tid & 63, wv = tid >> 6;
    for (int i = tid; i < 64 * 64; i += 512) {
        int k = i >> 6, nn = i & 63;
        w_lds[nn * PADK + k] = (_Float16)Wl[i];
        w_lds[nn * PADK + 64 + k] = (_Float16)Wr[i];
    }
    __syncthreads();
    int ngroups = (n + 15) >> 4;
    int g = blockIdx.x * WPB + wv;
    if (g >= ngroups) return;
    int m16 = lane & 15, quad = lane >> 4;
    int hf = lane >> 5, col = lane & 31;
    float bias[4];
#pragma unroll
    for (int nt = 0; nt < 4; nt++) bias[nt] = bl[nt * 16 + m16];
    _Float16* my_in = in_lds[wv];
    const unsigned* hin32 = (const unsigned*)hin;
    const half4v* hin4v = (const half4v*)hin;
    int nd0 = g << 4;
    int nclamp = n - 1 - nd0;  // >= 0
    int idx = nd0 + lane;
    int rr = (lane <= 16) ? row_ptr[min(idx, n)] : 0;
    float ig = (lane < 16) ? inv_deg[min(idx, n - 1)] : 0.0f;

#pragma unroll
    for (int jp = 0; jp < 8; jp++) {
        int j2 = jp << 1;
        int nd = nd0 + min(j2 + hf, nclamp);
        unsigned u = hin32[(size_t)nd * 32 + col];
        ((unsigned*)(my_in + (j2 + hf) * PADK + 64))[col] = u;
    }

    int ef[16];
#pragma unroll
    for (int j = 0; j < 16; j++) {
        int jj = min(j, nclamp);
        int s0 = __shfl(rr, jj), s1 = __shfl(rr, jj + 1);
        int cb = min(64, s1 - s0);
        ef[j] = (lane < cb) ? csr_src[s0 + lane] : n;
    }

#pragma unroll
    for (int jp = 0; jp < 8; jp++) {
        int j2 = jp << 1;
        int jjA = min(j2, nclamp), jjB = min(j2 + 1, nclamp);
        int s0A = __shfl(rr, jjA), s1A = __shfl(rr, jjA + 1);
        int s0B = __shfl(rr, jjB), s1B = __shfl(rr, jjB + 1);
        float idgA = __shfl(ig, jjA), idgB = __shfl(ig, jjB);
        int cbA = min(64, s1A - s0A), cbB = min(64, s1B - s0B);
        floatx4 accA = {0.f, 0.f, 0.f, 0.f};
        floatx4 accB = {0.f, 0.f, 0.f, 0.f};
        {
            half4v vA[4], vB[4];
            LOAD4(ef[j2], 0, vA);
            LOAD4(ef[j2 + 1], 0, vB);
            ACC4(vA, accA);
            ACC4(vB, accB);
        }
        if (cbA > 16) {
            half4v v0[4];
            LOAD4(ef[j2], 16, v0);
            ACC4(v0, accA);
            if (cbA > 32) { half4v v1[4]; LOAD4(ef[j2], 32, v1); ACC4(v1, accA); }
            if (cbA > 48) { half4v v2[4]; LOAD4(ef[j2], 48, v2); ACC4(v2, accA); }
        }
        if (cbB > 16) {
            half4v v0[4];
            LOAD4(ef[j2 + 1], 16, v0);
            ACC4(v0, accB);
            if (cbB > 32) { half4v v1[4]; LOAD4(ef[j2 + 1], 32, v1); ACC4(v1, accB); }
            if (cbB > 48) { half4v v2[4]; LOAD4(ef[j2 + 1], 48, v2); ACC4(v2, accB); }
        }
        for (int base_ = s0A + 64; base_ < s1A; base_ += 64) {
            int cb = min(64, s1A - base_);
            int ei = (lane < cb) ? csr_src[base_ + lane] : n;
            for (int i0 = 0; i0 < cb; i0 += 16) {
                half4v vt[4];
                LOAD4(ei, i0, vt);
                ACC4(vt, accA);
            }
        }
        for (int base_ = s0B + 64; base_ < s1B; base_ += 64) {
            int cb = min(64, s1B - base_);
            int ei = (lane < cb) ? csr_src[base_ + lane] : n;
            for (int i0 = 0; i0 < cb; i0 += 16) {
                half4v vt[4];
                LOAD4(ei, i0, vt);
                ACC4(vt, accB);
            }
        }
        accA.x += __shfl_xor(accA.x, 16); accA.y += __shfl_xor(accA.y, 16);
        accA.z += __shfl_xor(accA.z, 16); accA.w += __shfl_xor(accA.w, 16);
        accA.x += __shfl_xor(accA.x, 32); accA.y += __shfl_xor(accA.y, 32);
        accA.z += __shfl_xor(accA.z, 32); accA.w += __shfl_xor(accA.w, 32);
        accB.x += __shfl_xor(accB.x, 16); accB.y += __shfl_xor(accB.y, 16);
        accB.z += __shfl_xor(accB.z, 16); accB.w += __shfl_xor(accB.w, 16);
        accB.x += __shfl_xor(accB.x, 32); accB.y += __shfl_xor(accB.y, 32);
        accB.z += __shfl_xor(accB.z, 32); accB.w += __shfl_xor(accB.w, 32);
        if (quad == 0) {
            half4v hw;
            hw[0] = (_Float16)(accA.x * idgA);
            hw[1] = (_Float16)(accA.y * idgA);
            hw[2] = (_Float16)(accA.z * idgA);
            hw[3] = (_Float16)(accA.w * idgA);
            *(half4v*)(my_in + j2 * PADK + m16 * 4) = hw;
        } else if (quad == 1) {
            half4v hw;
            hw[0] = (_Float16)(accB.x * idgB);
            hw[1] = (_Float16)(accB.y * idgB);
            hw[2] = (_Float16)(accB.z * idgB);
            hw[3] = (_Float16)(accB.w * idgB);
            *(half4v*)(my_in + (j2 + 1) * PADK + m16 * 4) = hw;
        }
    }
    half8 afrag[4];
    const _Float16* abase = my_in + m16 * PADK + quad * 8;
#pragma unroll
    for (int ks = 0; ks < 4; ks++) afrag[ks] = *(const half8*)(abase + ks * 32);
    floatx4 accv[4];
#pragma unroll
    for (int nt = 0; nt < 4; nt++) {
        accv[nt].x = 0.f; accv[nt].y = 0.f; accv[nt].z = 0.f; accv[nt].w = 0.f;
    }
#pragma unroll
    for (int nt = 0; nt < 4; nt++) {
        const _Float16* bbase = w_lds + (nt * 16 + m16) * PADK + quad * 8;
#pragma unroll
        for (int ks = 0; ks < 4; ks++) {
            half8 bfrag = *(const half8*)(bbase + ks * 32);
            accv[nt] = __builtin_amdgcn_mfma_f32_16x16x32_f16(afrag[ks], bfrag, accv[nt], 0, 0, 0);
        }
    }
    // ---- fused pool epilogue ----
    int bFirst = batch[nd0];
    int bLast = batch[min(nd0 + 15, n - 1)];
    if (bFirst == bLast && nd0 + 15 < n) {
#pragma unroll
        for (int nt = 0; nt < 4; nt++) {
            float s = fmaxf(accv[nt][0] + bias[nt], 0.0f) + fmaxf(accv[nt][1] + bias[nt], 0.0f) +
                      fmaxf(accv[nt][2] + bias[nt], 0.0f) + fmaxf(accv[nt][3] + bias[nt], 0.0f);
            s += __shfl_xor(s, 16);
            s += __shfl_xor(s, 32);
            if (quad == 0) atomicAdd(&gsum[bFirst * 64 + nt * 16 + m16], s);
        }
    } else {
#pragma unroll
        for (int nt = 0; nt < 4; nt++) {
#pragma unroll
            for (int r = 0; r < 4; r++) {
                int node = nd0 + quad * 4 + r;
                if (node < n) {
                    int bg = batch[node];
                    float v = fmaxf(accv[nt][r] + bias[nt], 0.0f);
                    atomicAdd(&gsum[bg * 64 + nt * 16 + m16], v);
                }
            }
        }
    }
}

// ---------------- head (1024 threads) ----------------
__global__ __launch_bounds__(1024) void gnn_head(const float* __restrict__ gsum,
                                                 const float* __restrict__ gcnt,
                                                 const float* __restrict__ l0W,
                                                 const float* __restrict__ l0b,
                                                 const float* __restrict__ outW,
                                                 const float* __restrict__ outb,
                                                 float* __restrict__ out, int G, int OUT) {
    __shared__ float gm[64 * 64];
    __shared__ float t2[64 * 64];
    int tid = threadIdx.x;
    for (int i = tid; i < G * 64; i += 1024) {
        int r = i >> 6;
        gm[i] = gsum[i] / fmaxf(gcnt[r], 1.0f);
    }
    __syncthreads();
    for (int i = tid; i < G * 64; i += 1024) {
        int r = i >> 6, c = i & 63;
        float s = l0b[c];
#pragma unroll 8
        for (int k = 0; k < 64; k++) s += gm[(r << 6) + k] * l0W[(k << 6) + c];
        t2[i] = fmaxf(s, 0.0f);
    }
    __syncthreads();
    for (int i = tid; i < G * OUT; i += 1024) {
        int r = i / OUT, c = i - r * OUT;
        float s = outb[c];
#pragma unroll 8
        for (int k = 0; k < 64; k++) s += t2[(r << 6) + k] * outW[k * OUT + c];
        out[i] = s;
    }
}

extern "C" void kernel_launch(void* const* d_in, const int* in_sizes, int n_in,
                              void* d_out, int out_size, void* d_ws, size_t ws_size,
                              hipStream_t stream) {
    const float* x = (const float*)d_in[0];
    const int* ei = (const int*)d_in[1];
    const int* batch = (const int*)d_in[2];
    const float* Wl[3] = {(const float*)d_in[3], (const float*)d_in[6], (const float*)d_in[9]};
    const float* bl[3] = {(const float*)d_in[4], (const float*)d_in[7], (const float*)d_in[10]};
    const float* Wr[3] = {(const float*)d_in[5], (const float*)d_in[8], (const float*)d_in[11]};
    const float* l0W = (const float*)d_in[12];
    const float* l0b = (const float*)d_in[13];
    const float* outW = (const float*)d_in[14];
    const float* outb = (const float*)d_in[15];

    int N = in_sizes[2];
    int E = in_sizes[1] / 2;
    int OUT = 10;
    int G = out_size / OUT;
    const int* src = ei;
    const int* dst = ei + E;
    int NBKT = (N + BNODES - 1) >> BSH;

    char* ws = (char*)d_ws;
    size_t off = 0;
    auto alloc = [&](size_t b) -> char* {
        char* p = ws + off;
        off = (off + b + 255) & ~(size_t)255;
        return p;
    };
    int* row_ptr = (int*)alloc((size_t)(N + 1) * 4);
    int* csr_src = (int*)alloc((size_t)E * 4);
    float* inv_deg = (float*)alloc((size_t)N * 4);
    // contiguous zero region: bkt_cnt | gcnt | gsum (one memset)
    size_t zoff = off;
    int* bkt_cnt = (int*)alloc((size_t)NBKT * 4);
    float* gcnt = (float*)alloc((size_t)G * 4);
    float* gsum = (float*)alloc((size_t)G * 64 * 4);
    size_t zlen = off - zoff;
    int* bkt_base = (int*)alloc((size_t)(NBKT + 1) * 4);
    int* hist_all = (int*)alloc((size_t)HIST_BLOCKS * HSTRIDE * 4);
    int* blk_base_all = (int*)alloc((size_t)HIST_BLOCKS * HSTRIDE * 4);
    unsigned int* pairs = (unsigned int*)alloc((size_t)E * 4);
    __half* x16 = (__half*)alloc((size_t)(N + 1) * 64 * 2);  // +1 sentinel row
    __half* hA = (__half*)alloc((size_t)(N + 1) * 64 * 2);
    __half* hB = (__half*)alloc((size_t)(N + 1) * 64 * 2);

    hipMemsetAsync(ws + zoff, 0, zlen, stream);

    int n4 = N * 64 / 4;
    int pre_blocks = HIST_BLOCKS + (n4 + 255) / 256;
    gnn_pre<<<pre_blocks, 256, 0, stream>>>(dst, bkt_cnt, NBKT, E, batch, gcnt, N,
                                            (const float4*)x, (ushort4*)x16, n4,
                                            x16, hA, hB, hist_all);
    gnn_scan2<<<NBKT, 256, 0, stream>>>(hist_all, bkt_cnt, bkt_base, row_ptr,
                                        blk_base_all, NBKT, N);
    gnn_bkt_scatter<<<SC_BLOCKS, 256, 0, stream>>>(src, dst, blk_base_all, pairs, E, NBKT);
    gnn_bkt_csr<<<NBKT, 256, 0, stream>>>(pairs, bkt_base, row_ptr, inv_deg, csr_src, N);

    int ngroups = (N + 15) >> 4;
    int sage_blocks = (ngroups + WPB - 1) / WPB;
    gnn_sage<<<sage_blocks, 512, 0, stream>>>(x16, hA, row_ptr, csr_src, inv_deg,
                                              Wl[0], bl[0], Wr[0], N);
    gnn_sage<<<sage_blocks, 512, 0, stream>>>(hA, hB, row_ptr, csr_src, inv_deg,
                                              Wl[1], bl[1], Wr[1], N);
    gnn_sage_pool<<<sage_blocks, 512, 0, stream>>>(hB, row_ptr, csr_src, inv_deg,
                                                   Wl[2], bl[2], Wr[2], batch, gsum, N);

    gnn_head<<<1, 1024, 0, stream>>>(gsum, gcnt, l0W, l0b, outW, outb, (float*)d_out, G, OUT);
}